// Round 1
// baseline (624.148 us; speedup 1.0000x reference)
//
#include <hip/hip_runtime.h>
#include <math.h>

#define LEAKY 0.01f

// One thread per edge. h[32] in VGPRs; W1/b1/W2/b2 are wave-uniform reads
// (compiler emits s_load + FMA-with-SGPR-operand). z rows gathered as float4.
__global__ __launch_bounds__(256) void edge_mlp_f32(
    const float* __restrict__ z, const int* __restrict__ idx,
    const float* __restrict__ W1, const float* __restrict__ b1,
    const float* __restrict__ W2, const float* __restrict__ b2,
    float* __restrict__ out, int E)
{
    int e = blockIdx.x * blockDim.x + threadIdx.x;
    if (e >= E) return;
    int s = idx[e];
    int d = idx[E + e];
    const float4* zs = reinterpret_cast<const float4*>(z + (size_t)s * 64);
    const float4* zd = reinterpret_cast<const float4*>(z + (size_t)d * 64);

    float h[32];
    #pragma unroll
    for (int j = 0; j < 32; ++j) h[j] = b1[j];

    // concat row = [z[s] (rows 0..63 of W1), z[d] (rows 64..127 of W1)]
    #pragma unroll 4
    for (int k4 = 0; k4 < 16; ++k4) {
        float4 a = zs[k4];
        float4 b = zd[k4];
        const float* wa0 = W1 + (4 * k4 + 0) * 32;
        const float* wa1 = W1 + (4 * k4 + 1) * 32;
        const float* wa2 = W1 + (4 * k4 + 2) * 32;
        const float* wa3 = W1 + (4 * k4 + 3) * 32;
        const float* wb0 = W1 + (64 + 4 * k4 + 0) * 32;
        const float* wb1 = W1 + (64 + 4 * k4 + 1) * 32;
        const float* wb2 = W1 + (64 + 4 * k4 + 2) * 32;
        const float* wb3 = W1 + (64 + 4 * k4 + 3) * 32;
        #pragma unroll
        for (int j = 0; j < 32; ++j) {
            float acc = h[j];
            acc = fmaf(a.x, wa0[j], acc);
            acc = fmaf(a.y, wa1[j], acc);
            acc = fmaf(a.z, wa2[j], acc);
            acc = fmaf(a.w, wa3[j], acc);
            acc = fmaf(b.x, wb0[j], acc);
            acc = fmaf(b.y, wb1[j], acc);
            acc = fmaf(b.z, wb2[j], acc);
            acc = fmaf(b.w, wb3[j], acc);
            h[j] = acc;
        }
    }

    float acc = b2[0];
    #pragma unroll
    for (int j = 0; j < 32; ++j) {
        float hv = h[j];
        hv = (hv >= 0.0f) ? hv : LEAKY * hv;
        acc = fmaf(hv, W2[j], acc);
    }
    out[e] = tanhf(acc);
}

extern "C" void kernel_launch(void* const* d_in, const int* in_sizes, int n_in,
                              void* d_out, int out_size, void* d_ws, size_t ws_size,
                              hipStream_t stream) {
    const float* z  = (const float*)d_in[0];
    const int*   idx = (const int*)d_in[1];
    const float* W1 = (const float*)d_in[2];
    const float* b1 = (const float*)d_in[3];
    const float* W2 = (const float*)d_in[4];
    const float* b2 = (const float*)d_in[5];
    float* out = (float*)d_out;

    const int E = out_size;  // 3,200,000
    const int threads = 256;
    const int blocks = (E + threads - 1) / threads;
    edge_mlp_f32<<<blocks, threads, 0, stream>>>(z, idx, W1, b1, W2, b2, out, E);
}

// Round 2
// 195.764 us; speedup vs baseline: 3.1883x; 3.1883x over previous
//
#include <hip/hip_runtime.h>
#include <hip/hip_fp16.h>
#include <math.h>

#define LEAKY 0.01f

// ---------------------------------------------------------------------------
// Kernel 1: per-node projections.
//   U[n][j] = sum_k z[n][k] * W1[k][j]      + b1[j]   (k in [0,64))
//   V[n][j] = sum_k z[n][k] * W1[64+k][j]             (k in [0,64))
// stored fp16 (64 B per row). hf (which half of W1) is uniform per block so
// W1 reads stay scalar (s_load).
// ---------------------------------------------------------------------------
__global__ __launch_bounds__(256) void node_proj(
    const float* __restrict__ z, const float* __restrict__ W1,
    const float* __restrict__ b1, __half* __restrict__ U, __half* __restrict__ V,
    int N, int nbU)
{
    int hf = (blockIdx.x >= nbU) ? 1 : 0;
    int n = (blockIdx.x - hf * nbU) * blockDim.x + threadIdx.x;
    if (n >= N) return;

    const float4* zr = reinterpret_cast<const float4*>(z + (size_t)n * 64);
    const float* W = W1 + (size_t)hf * 64 * 32;

    float acc[32];
    #pragma unroll
    for (int j = 0; j < 32; ++j) acc[j] = hf ? 0.0f : b1[j];

    #pragma unroll 4
    for (int k4 = 0; k4 < 16; ++k4) {
        float4 a = zr[k4];
        const float* w0 = W + (4 * k4 + 0) * 32;
        const float* w1 = W + (4 * k4 + 1) * 32;
        const float* w2 = W + (4 * k4 + 2) * 32;
        const float* w3 = W + (4 * k4 + 3) * 32;
        #pragma unroll
        for (int j = 0; j < 32; ++j) {
            float t = acc[j];
            t = fmaf(a.x, w0[j], t);
            t = fmaf(a.y, w1[j], t);
            t = fmaf(a.z, w2[j], t);
            t = fmaf(a.w, w3[j], t);
            acc[j] = t;
        }
    }

    // pack 32 floats -> 32 fp16 -> 4 x uint4 stores (64 B contiguous)
    uint w[16];
    #pragma unroll
    for (int i = 0; i < 16; ++i) {
        __half2 h2 = __floats2half2_rn(acc[2 * i], acc[2 * i + 1]);
        w[i] = *reinterpret_cast<uint*>(&h2);
    }
    __half* dstrow = (hf ? V : U) + (size_t)n * 32;
    uint4* dst = reinterpret_cast<uint4*>(dstrow);
    dst[0] = make_uint4(w[0], w[1], w[2], w[3]);
    dst[1] = make_uint4(w[4], w[5], w[6], w[7]);
    dst[2] = make_uint4(w[8], w[9], w[10], w[11]);
    dst[3] = make_uint4(w[12], w[13], w[14], w[15]);
}

__device__ inline float2 h2f(uint w) {
    __half2 h = *reinterpret_cast<__half2*>(&w);
    return __half22float2(h);
}

// ---------------------------------------------------------------------------
// Kernel 2: per-edge decode. Gather u[s] (64 B) + v[d] (64 B), h = u+v,
// LeakyReLU, dot W2, tanh.
// ---------------------------------------------------------------------------
__global__ __launch_bounds__(256) void edge_decode(
    const int* __restrict__ idx,
    const __half* __restrict__ U, const __half* __restrict__ V,
    const float* __restrict__ W2, const float* __restrict__ b2,
    float* __restrict__ out, int E)
{
    int e = blockIdx.x * blockDim.x + threadIdx.x;
    if (e >= E) return;
    int s = idx[e];
    int d = idx[E + e];

    const uint4* us = reinterpret_cast<const uint4*>(U + (size_t)s * 32);
    const uint4* vd = reinterpret_cast<const uint4*>(V + (size_t)d * 32);

    uint uw[16], vw[16];
    #pragma unroll
    for (int i = 0; i < 4; ++i) {
        uint4 a = us[i];
        uw[4 * i + 0] = a.x; uw[4 * i + 1] = a.y; uw[4 * i + 2] = a.z; uw[4 * i + 3] = a.w;
        uint4 b = vd[i];
        vw[4 * i + 0] = b.x; vw[4 * i + 1] = b.y; vw[4 * i + 2] = b.z; vw[4 * i + 3] = b.w;
    }

    float acc = b2[0];
    #pragma unroll
    for (int i = 0; i < 16; ++i) {
        float2 uu = h2f(uw[i]);
        float2 vv = h2f(vw[i]);
        float h0 = uu.x + vv.x;
        float h1 = uu.y + vv.y;
        h0 = (h0 >= 0.0f) ? h0 : LEAKY * h0;
        h1 = (h1 >= 0.0f) ? h1 : LEAKY * h1;
        acc = fmaf(h0, W2[2 * i], acc);
        acc = fmaf(h1, W2[2 * i + 1], acc);
    }
    out[e] = tanhf(acc);
}

// ---------------------------------------------------------------------------
// Fallback (round-1 kernel) if the workspace is too small for U/V.
// ---------------------------------------------------------------------------
__global__ __launch_bounds__(256) void edge_mlp_f32(
    const float* __restrict__ z, const int* __restrict__ idx,
    const float* __restrict__ W1, const float* __restrict__ b1,
    const float* __restrict__ W2, const float* __restrict__ b2,
    float* __restrict__ out, int E)
{
    int e = blockIdx.x * blockDim.x + threadIdx.x;
    if (e >= E) return;
    int s = idx[e];
    int d = idx[E + e];
    const float4* zs = reinterpret_cast<const float4*>(z + (size_t)s * 64);
    const float4* zd = reinterpret_cast<const float4*>(z + (size_t)d * 64);

    float h[32];
    #pragma unroll
    for (int j = 0; j < 32; ++j) h[j] = b1[j];

    #pragma unroll 4
    for (int k4 = 0; k4 < 16; ++k4) {
        float4 a = zs[k4];
        float4 b = zd[k4];
        const float* wa0 = W1 + (4 * k4 + 0) * 32;
        const float* wa1 = W1 + (4 * k4 + 1) * 32;
        const float* wa2 = W1 + (4 * k4 + 2) * 32;
        const float* wa3 = W1 + (4 * k4 + 3) * 32;
        const float* wb0 = W1 + (64 + 4 * k4 + 0) * 32;
        const float* wb1 = W1 + (64 + 4 * k4 + 1) * 32;
        const float* wb2 = W1 + (64 + 4 * k4 + 2) * 32;
        const float* wb3 = W1 + (64 + 4 * k4 + 3) * 32;
        #pragma unroll
        for (int j = 0; j < 32; ++j) {
            float acc = h[j];
            acc = fmaf(a.x, wa0[j], acc);
            acc = fmaf(a.y, wa1[j], acc);
            acc = fmaf(a.z, wa2[j], acc);
            acc = fmaf(a.w, wa3[j], acc);
            acc = fmaf(b.x, wb0[j], acc);
            acc = fmaf(b.y, wb1[j], acc);
            acc = fmaf(b.z, wb2[j], acc);
            acc = fmaf(b.w, wb3[j], acc);
            h[j] = acc;
        }
    }

    float acc = b2[0];
    #pragma unroll
    for (int j = 0; j < 32; ++j) {
        float hv = h[j];
        hv = (hv >= 0.0f) ? hv : LEAKY * hv;
        acc = fmaf(hv, W2[j], acc);
    }
    out[e] = tanhf(acc);
}

extern "C" void kernel_launch(void* const* d_in, const int* in_sizes, int n_in,
                              void* d_out, int out_size, void* d_ws, size_t ws_size,
                              hipStream_t stream) {
    const float* z  = (const float*)d_in[0];
    const int*   idx = (const int*)d_in[1];
    const float* W1 = (const float*)d_in[2];
    const float* b1 = (const float*)d_in[3];
    const float* W2 = (const float*)d_in[4];
    const float* b2 = (const float*)d_in[5];
    float* out = (float*)d_out;

    const int E = out_size;            // 3,200,000
    const int N = in_sizes[0] / 64;    // 100,000 nodes

    size_t need = (size_t)2 * N * 32 * sizeof(__half);  // 12.8 MB
    if (ws_size >= need) {
        __half* U = (__half*)d_ws;
        __half* V = U + (size_t)N * 32;
        const int threads = 256;
        const int nbU = (N + threads - 1) / threads;
        node_proj<<<2 * nbU, threads, 0, stream>>>(z, W1, b1, U, V, N, nbU);
        edge_decode<<<(E + threads - 1) / threads, threads, 0, stream>>>(
            idx, U, V, W2, b2, out, E);
    } else {
        const int threads = 256;
        edge_mlp_f32<<<(E + threads - 1) / threads, threads, 0, stream>>>(
            z, idx, W1, b1, W2, b2, out, E);
    }
}